// Round 16
// baseline (26.733 us; speedup 1.0000x reference)
//
#include <hip/hip_runtime.h>

#define T_DIM 1024
#define B_DIM 32
#define C_DIM 512
#define PROWS 64    // p-rows per block (R12-validated); grid (16,32) = 512 blocks
#define NTHREADS 512 // 8 waves: double TLP vs R12/R15 at same preamble count

typedef float f32x4 __attribute__((ext_vector_type(4)));

// R15 skeleton at 512 threads/block.
//   A: waves 0-3 scan labels (4/thread) + compaction; a[0],a[1] prefetched
//   B: means, 2 rows per wave per round across 8 waves (1 round for t<=16)
//   C: issue remaining 14 audio f32x4/thread; 64-thread serial product
//   D: mul + store burst
__global__ __launch_bounds__(NTHREADS) void k_fused(const float* __restrict__ video,
                                                    const float* __restrict__ audio,
                                                    const int* __restrict__ labels,
                                                    float* __restrict__ out) {
    int b     = blockIdx.y;
    int pBase = blockIdx.x * PROWS;
    int tid   = threadIdx.x;
    int lane  = tid & 63;
    int wave  = tid >> 6;               // 0..7
    __shared__ float vm[T_DIM];
    __shared__ int   pos[T_DIM];
    __shared__ int   waveTot[4];
    __shared__ float sscale[PROWS];

    // streaming geometry: thread handles rows k = 4*i + quarter, i = 0..15
    int quarter = tid >> 7;             // 0..3
    int c4      = tid & 127;
    const int rstep4 = 4 * B_DIM * (C_DIM / 4);   // 4 p-rows in f32x4 units
    int base0 = ((pBase + quarter) * B_DIM + b) * (C_DIM / 4) + c4;
    const f32x4* ain  = (const f32x4*)audio;
    f32x4*       aout = (f32x4*)out;

    // ---- phase A: prefetch first 2 audio rows; waves 0-3 scan labels ----
    f32x4 a[16];
    a[0] = ain[base0];
    a[1] = ain[base0 + rstep4];

    int cnt = 0, incl = 0, p0 = tid * 4;
    int f0 = 0, f1 = 0, f2 = 0, f3 = 0;
    if (tid < 256) {
        int4 lv = *(const int4*)(labels + b * T_DIM + p0);
        f0 = (lv.x == 1); f1 = (lv.y == 1); f2 = (lv.z == 1); f3 = (lv.w == 1);
        cnt = f0 + f1 + f2 + f3;
        incl = cnt;
        #pragma unroll
        for (int off = 1; off < 64; off <<= 1) {
            int n = __shfl_up(incl, off);
            if (lane >= off) incl += n;
        }
        if (lane == 63) waveTot[wave] = incl;
    }
    __syncthreads();

    int t = waveTot[0] + waveTot[1] + waveTot[2] + waveTot[3];
    if (tid < 256) {
        int waveOff = 0;
        for (int w = 0; w < wave; ++w) waveOff += waveTot[w];
        int r = waveOff + incl - cnt;
        if (f0) pos[r++] = p0 + 0;
        if (f1) pos[r++] = p0 + 1;
        if (f2) pos[r++] = p0 + 2;
        if (f3) pos[r++] = p0 + 3;
    }
    __syncthreads();

    // ---- phase B: means, 2 rows per wave per round across 8 waves ----
    for (int base = 0; base < t; base += 16) {
        int rr0 = base + wave;          // waves 0..7
        int rr1 = rr0 + 8;
        int rc0 = rr0 < t ? rr0 : 0;
        int rc1 = rr1 < t ? rr1 : 0;
        const float* s0p = video + (size_t)pos[rc0] * (B_DIM * C_DIM) + b * C_DIM;
        const float* s1p = video + (size_t)pos[rc1] * (B_DIM * C_DIM) + b * C_DIM;
        float4 x0a = *(const float4*)(s0p + lane * 4);
        float4 x0b = *(const float4*)(s0p + 256 + lane * 4);
        float4 x1a = *(const float4*)(s1p + lane * 4);
        float4 x1b = *(const float4*)(s1p + 256 + lane * 4);
        float v0 = x0a.x + x0a.y + x0a.z + x0a.w + x0b.x + x0b.y + x0b.z + x0b.w;
        float v1 = x1a.x + x1a.y + x1a.z + x1a.w + x1b.x + x1b.y + x1b.z + x1b.w;
        #pragma unroll
        for (int off = 32; off; off >>= 1) {
            v0 += __shfl_xor(v0, off);
            v1 += __shfl_xor(v1, off);
        }
        if (lane == 0) {
            if (rr0 < t) vm[rr0] = v0 * (1.0f / C_DIM);
            if (rr1 < t) vm[rr1] = v1 * (1.0f / C_DIM);
        }
    }
    __syncthreads();

    // ---- phase C: issue remaining 14 audio f32x4, then windowed product ----
    #pragma unroll
    for (int i = 2; i < 16; ++i)
        a[i] = ain[base0 + i * rstep4];

    if (tid < PROWS) {
        int p  = pBase + tid;
        int lo = p - (T_DIM - t); if (lo < 0) lo = 0;
        int hi = p < (t - 1) ? p : (t - 1);
        float s = 1.0f;
        for (int m = lo; m <= hi; ++m) s *= vm[m];
        sscale[tid] = s;
    }
    __syncthreads();

    // ---- phase D: mul + store burst ----
    #pragma unroll
    for (int i = 0; i < 16; ++i) {
        float s = sscale[4 * i + quarter];
        aout[base0 + i * rstep4] = a[i] * s;
    }
}

extern "C" void kernel_launch(void* const* d_in, const int* in_sizes, int n_in,
                              void* d_out, int out_size, void* d_ws, size_t ws_size,
                              hipStream_t stream) {
    const float* video  = (const float*)d_in[0];
    const float* audio  = (const float*)d_in[1];
    const int*   labels = (const int*)d_in[2];
    float* out = (float*)d_out;

    dim3 grid(T_DIM / PROWS, B_DIM);
    k_fused<<<grid, NTHREADS, 0, stream>>>(video, audio, labels, out);
}